// Round 16
// baseline (55.793 us; speedup 1.0000x reference)
//
#include <hip/hip_runtime.h>
#include <stdint.h>

#define MARGIN 0.3f
#define NROWS 4096
#define DIM   2048
#define ROWB  1024                  // fp4: DIM/2 bytes per row
#define PLANE (NROWS * 16)          // 65536 B: one 16B-column plane
#define KSTEP (4 * PLANE)           // byte stride between K-steps (4 planes)
#define NKS   16
#define BT    128
#define NB    (NROWS / BT)          // 32
#define NBLK  (NB * (NB + 1) / 2)   // 528 (fallback tiling)
#define NBLK2 1056                  // 64x128 upper-tri blocks: sum(2bj+2), %8==0

typedef float f32x4 __attribute__((ext_vector_type(4)));
typedef int   i32x4 __attribute__((ext_vector_type(4)));
typedef int   i32x8 __attribute__((ext_vector_type(8)));
typedef short s16x8 __attribute__((ext_vector_type(8)));

__device__ __forceinline__ ushort f32_to_bf16(float f) {
  uint32_t u = __float_as_uint(f);
  return (ushort)((u + 0x7FFFu + ((u >> 16) & 1u)) >> 16);
}

// e2m1 quantizer to grid {0,.5,1,1.5,2,3,4,6}, clamp at 6.
__device__ __forceinline__ unsigned f32_to_fp4(float y) {
  unsigned s = (__float_as_uint(y) >> 31) << 3;
  float a = fabsf(y);
  unsigned c;
  if      (a < 0.25f) c = 0;
  else if (a < 0.75f) c = 1;
  else if (a < 1.25f) c = 2;
  else if (a < 1.75f) c = 3;
  else if (a < 2.5f)  c = 4;
  else if (a < 3.5f)  c = 5;
  else if (a < 5.0f)  c = 6;
  else                c = 7;
  return s | c;
}

// ---------------------------------------------------------------------------
// prep16 (R12, verified fast): 16 rows per block, one wave per row. Lane l
// holds 32 CONTIGUOUS elems of its row -> one 16B plane-chunk after
// quantization; transpose via 16KB XOR-swizzled LDS, write plane-major in
// 256B-contiguous runs. Zeroes the accumulators.
// ---------------------------------------------------------------------------
__global__ __launch_bounds__(1024) void prep16(const float* __restrict__ in,
                                               unsigned char* __restrict__ pn,
                                               float* __restrict__ accum) {
  const int tid  = threadIdx.x;
  const int w    = tid >> 6;          // wave = row_local 0..15
  const int lane = tid & 63;
  const int row  = blockIdx.x * 16 + w;
  if (blockIdx.x == 0 && tid == 0) { accum[0] = 0.f; accum[1] = 0.f; }

  const float4* rp = (const float4*)(in + (size_t)row * DIM);
  float4 v[8];
  #pragma unroll
  for (int i = 0; i < 8; ++i) v[i] = rp[lane * 8 + i];   // 128B contiguous/lane

  float ss = 0.f;
  #pragma unroll
  for (int i = 0; i < 8; ++i)
    ss += v[i].x*v[i].x + v[i].y*v[i].y + v[i].z*v[i].z + v[i].w*v[i].w;
  #pragma unroll
  for (int off = 1; off < 64; off <<= 1) ss += __shfl_xor(ss, off);
  const float sc = 64.0f / fmaxf(sqrtf(ss), 1e-12f);     // norm * 2^6

  union { unsigned char bb[16]; int4 u; } q;
  #pragma unroll
  for (int i = 0; i < 8; ++i) {
    unsigned b0 = f32_to_fp4(v[i].x * sc) | (f32_to_fp4(v[i].y * sc) << 4);
    unsigned b1 = f32_to_fp4(v[i].z * sc) | (f32_to_fp4(v[i].w * sc) << 4);
    q.bb[2*i]   = (unsigned char)b0;
    q.bb[2*i+1] = (unsigned char)b1;
  }

  __shared__ int4 lt[1024];           // [row_local][chunk] with XOR swizzle
  lt[w * 64 + (lane ^ w)] = q.u;
  __syncthreads();

  const int p = tid >> 4, rl = tid & 15;
  int4 val = lt[rl * 64 + (p ^ rl)];
  *(int4*)(pn + (size_t)p * PLANE + ((size_t)blockIdx.x * 16 + rl) * 16) = val;
}

// ---------------------------------------------------------------------------
// tri_gemm: 64x128 upper-tri blocks (R8's verified partition: row-block bi of
// 64 rows, col-block bj of 128 cols, kept iff bi <= 2*bj+1 -> 1056 blocks).
// 256 threads = 4 waves; wave w owns the 64x32 band [bj*128+w*32, +32).
// 4224 waves ~= 4.1 waves/SIMD -- the TLP every prior round lacked (all were
// pinned at 2.06 waves/SIMD and all landed at 35-44us regardless of
// structure; exposed L2/L3 load latency needs wave-switching to hide).
// fp4 e2m1 via mfma_scale_f32_16x16x128_f8f6f4 (cbsz=blgp=4), scale 0x79 =
// 2^-6 -> acc = sim. No LDS/barriers; ROLLED loop (I-cache lesson, R12-14);
// intrinsic loads (compiler-tracked vmcnt); named 2-deep buffers.
// A-band (4 fragments) shared by all 4 waves -> L1 reuse x4.
// ---------------------------------------------------------------------------
__device__ __forceinline__ void ld6(const unsigned char* __restrict__ p,
                                    uint32_t voA, uint32_t voB,
                                    i32x4 fa[4], i32x4 fb[2]) {
  #pragma unroll
  for (int m = 0; m < 4; ++m)
    fa[m] = *(const i32x4*)(p + voA + m * 256);   // +16 rows per m
  #pragma unroll
  for (int n = 0; n < 2; ++n)
    fb[n] = *(const i32x4*)(p + voB + n * 256);
}

__device__ __forceinline__ void mm8(const i32x4 fa[4], const i32x4 fb[2],
                                    f32x4 acc[4][2]) {
  const i32x4 z4 = {0, 0, 0, 0};
  i32x8 bn[2];
  #pragma unroll
  for (int n = 0; n < 2; ++n)
    bn[n] = __builtin_shufflevector(fb[n], z4, 0, 1, 2, 3, 4, 5, 6, 7);
  #pragma unroll
  for (int m = 0; m < 4; ++m) {
    i32x8 am = __builtin_shufflevector(fa[m], z4, 0, 1, 2, 3, 4, 5, 6, 7);
    #pragma unroll
    for (int n = 0; n < 2; ++n)
      acc[m][n] = __builtin_amdgcn_mfma_scale_f32_16x16x128_f8f6f4(
          am, bn[n], acc[m][n],
          4, 4,                      // cbsz=fp4(e2m1), blgp=fp4(e2m1)
          0, 0x79797979,             // scale_a: e8m0 = 2^-6 everywhere
          0, 0x79797979);            // scale_b: e8m0 = 2^-6 everywhere
  }
}

__global__ __launch_bounds__(256) void tri_gemm(const unsigned char* __restrict__ pn,
                                                float* __restrict__ accum) {
  // XCD-aware bijective swizzle (NBLK2 % 8 == 0)
  const int b = blockIdx.x;
  int t = (b & 7) * (NBLK2 / 8) + (b >> 3);
  int bj = 0;
  while (t >= 2 * bj + 2) { t -= 2 * bj + 2; ++bj; }
  const int bi = t;                   // 0 .. 2*bj+1

  const int tid  = threadIdx.x;
  const int lane = tid & 63;
  const int w    = tid >> 6;          // 0..3 : 32-col band
  const int fr   = lane & 15;         // fragment row within 16
  const int gq   = lane >> 4;         // 16B k-group within the 64B K-step

  f32x4 acc[4][2] = {};
  const int rowA = bi * 64;
  const int rowB = bj * BT + w * 32;

  uint32_t voA = (uint32_t)gq * PLANE + (uint32_t)(rowA + fr) * 16;
  uint32_t voB = (uint32_t)gq * PLANE + (uint32_t)(rowB + fr) * 16;

  i32x4 fa0[4], fb0[2], fa1[4], fb1[2];

  // prologue: K-step 0
  ld6(pn, voA, voB, fa0, fb0);
  voA += KSTEP; voB += KSTEP;

  #pragma unroll 1
  for (int i = 0; i < 8; ++i) {
    ld6(pn, voA, voB, fa1, fb1);      // load step 2i+1 under compute of 2i
    voA += KSTEP; voB += KSTEP;
    mm8(fa0, fb0, acc);
    if (i != 7) {                     // load step 2i+2 under compute of 2i+1
      ld6(pn, voA, voB, fa0, fb0);
      voA += KSTEP; voB += KSTEP;
    }
    mm8(fa1, fb1, acc);
  }

  // ---- epilogue: mask + reduce (C/D layout is shape-determined) ----
  float lsum = 0.f, lcnt = 0.f;
  #pragma unroll
  for (int m = 0; m < 4; ++m) {
    #pragma unroll
    for (int n = 0; n < 2; ++n) {
      #pragma unroll
      for (int r = 0; r < 4; ++r) {
        int gi = rowA + m * 16 + gq * 4 + r;
        int gj = rowB + n * 16 + fr;
        float s = acc[m][n][r];
        if (gi < gj && s > MARGIN) { lsum += s - MARGIN; lcnt += 1.f; }
      }
    }
  }
  #pragma unroll
  for (int off = 32; off; off >>= 1) {
    lsum += __shfl_down(lsum, off);
    lcnt += __shfl_down(lcnt, off);
  }
  __shared__ float rs[4], rc[4];
  if (lane == 0) { rs[w] = lsum; rc[w] = lcnt; }
  __syncthreads();
  if (tid == 0) {
    atomicAdd(&accum[0], rs[0] + rs[1] + rs[2] + rs[3]);
    atomicAdd(&accum[1], rc[0] + rc[1] + rc[2] + rc[3]);
  }
}

// ---------------------------------------------------------------------------
// Fallback (tiny workspace): bf16 on-the-fly convert (verified R2 structure).
// ---------------------------------------------------------------------------
__global__ __launch_bounds__(256) void prep_inv(const float* __restrict__ in,
                                                float* __restrict__ invn,
                                                float* __restrict__ accum) {
  const int row = blockIdx.x;
  const int tid = threadIdx.x;
  if (row == 0 && tid == 0) { accum[0] = 0.f; accum[1] = 0.f; }
  const float4* rp = (const float4*)(in + (size_t)row * DIM);
  float4 v0 = rp[tid * 2];
  float4 v1 = rp[tid * 2 + 1];
  float ss = v0.x*v0.x + v0.y*v0.y + v0.z*v0.z + v0.w*v0.w
           + v1.x*v1.x + v1.y*v1.y + v1.z*v1.z + v1.w*v1.w;
  #pragma unroll
  for (int off = 32; off; off >>= 1) ss += __shfl_down(ss, off);
  __shared__ float wred[4];
  const int lane = tid & 63, w = tid >> 6;
  if (lane == 0) wred[w] = ss;
  __syncthreads();
  if (tid == 0)
    invn[row] = 1.0f / fmaxf(sqrtf(wred[0] + wred[1] + wred[2] + wred[3]), 1e-12f);
}

__global__ __launch_bounds__(256) void tri_gemm_fly(const float* __restrict__ inF,
                                                    const float* __restrict__ invn,
                                                    float* __restrict__ accum) {
  enum { FBK = 64 };
  int t = blockIdx.x, bi = 0;
  while (t >= NB - bi) { t -= NB - bi; ++bi; }
  const int bj = bi + t;

  __shared__ __align__(16) ushort Asm[BT * FBK];
  __shared__ __align__(16) ushort Bsm[BT * FBK];

  const int tid  = threadIdx.x;
  const int lane = tid & 63;
  const int w    = tid >> 6;
  const int wr   = w >> 1, wc = w & 1;

  f32x4 acc[4][4] = {};
  const int rowA = bi * BT, rowB = bj * BT;

  for (int k0 = 0; k0 < DIM; k0 += FBK) {
    if (k0) __syncthreads();
    #pragma unroll
    for (int p = 0; p < 8; ++p) {
      int c   = p * 256 + tid;
      int isB = c >> 10;
      int cc  = c & 1023;
      int r   = cc >> 3;
      int s   = cc & 7;
      const int grow = (isB ? rowB : rowA) + r;
      const float4* src = (const float4*)(inF + (size_t)grow * DIM + k0 + s * 8);
      float4 v0 = src[0], v1 = src[1];
      int4 pack;
      ushort* h = (ushort*)&pack;
      h[0] = f32_to_bf16(v0.x); h[1] = f32_to_bf16(v0.y);
      h[2] = f32_to_bf16(v0.z); h[3] = f32_to_bf16(v0.w);
      h[4] = f32_to_bf16(v1.x); h[5] = f32_to_bf16(v1.y);
      h[6] = f32_to_bf16(v1.z); h[7] = f32_to_bf16(v1.w);
      *(int4*)((isB ? Bsm : Asm) + r * FBK + (s ^ (r & 7)) * 8) = pack;
    }
    __syncthreads();

    s16x8 af[2][4], bfv[2][4];
    const int fr = lane & 15, hi = lane >> 4;
    #pragma unroll
    for (int kk = 0; kk < 2; ++kk)
      #pragma unroll
      for (int m = 0; m < 4; ++m) {
        const int ra = wr * 64 + m * 16 + fr;
        af[kk][m] = *(const s16x8*)(Asm + ra * FBK + ((kk * 4 + hi) ^ (ra & 7)) * 8);
        const int rb = wc * 64 + m * 16 + fr;
        bfv[kk][m] = *(const s16x8*)(Bsm + rb * FBK + ((kk * 4 + hi) ^ (rb & 7)) * 8);
      }
    #pragma unroll
    for (int kk = 0; kk < 2; ++kk)
      #pragma unroll
      for (int m = 0; m < 4; ++m)
        #pragma unroll
        for (int n = 0; n < 4; ++n)
          acc[m][n] = __builtin_amdgcn_mfma_f32_16x16x32_bf16(af[kk][m], bfv[kk][n],
                                                              acc[m][n], 0, 0, 0);
  }

  float lsum = 0.f, lcnt = 0.f;
  const int gib = rowA + wr * 64;
  const int gjb = rowB + wc * 64;
  #pragma unroll
  for (int m = 0; m < 4; ++m)
    #pragma unroll
    for (int n = 0; n < 4; ++n)
      #pragma unroll
      for (int r = 0; r < 4; ++r) {
        int gi = gib + m * 16 + (lane >> 4) * 4 + r;
        int gj = gjb + n * 16 + (lane & 15);
        float s = acc[m][n][r] * invn[gi] * invn[gj];
        if (gi < gj && s > MARGIN) { lsum += s - MARGIN; lcnt += 1.f; }
      }
  #pragma unroll
  for (int off = 32; off; off >>= 1) {
    lsum += __shfl_down(lsum, off);
    lcnt += __shfl_down(lcnt, off);
  }
  __shared__ float rs[4], rc[4];
  if (lane == 0) { rs[w] = lsum; rc[w] = lcnt; }
  __syncthreads();
  if (tid == 0) {
    atomicAdd(&accum[0], rs[0] + rs[1] + rs[2] + rs[3]);
    atomicAdd(&accum[1], rc[0] + rc[1] + rc[2] + rc[3]);
  }
}

__global__ void finalize_kernel(const float* __restrict__ accum, float* __restrict__ out) {
  if (threadIdx.x == 0) out[0] = (accum[1] < 0.5f) ? 0.0f : accum[0] / accum[1];
}

extern "C" void kernel_launch(void* const* d_in, const int* in_sizes, int n_in,
                              void* d_out, int out_size, void* d_ws, size_t ws_size,
                              hipStream_t stream) {
  const float* in = (const float*)d_in[0];
  float* out = (float*)d_out;
  const size_t pn_bytes = (size_t)NROWS * ROWB;   // fp4: 4.2 MB (64 planes)

  if (ws_size >= pn_bytes + 2 * sizeof(float)) {
    unsigned char* pn = (unsigned char*)d_ws;
    float* accum = (float*)((char*)d_ws + pn_bytes);
    prep16<<<NROWS / 16, 1024, 0, stream>>>(in, pn, accum);
    tri_gemm<<<NBLK2, 256, 0, stream>>>(pn, accum);
    finalize_kernel<<<1, 64, 0, stream>>>(accum, out);
  } else {
    float* invn  = (float*)d_ws;
    float* accum = (float*)((char*)d_ws + NROWS * sizeof(float));
    prep_inv<<<NROWS, 256, 0, stream>>>(in, invn, accum);
    tri_gemm_fly<<<NBLK, 256, 0, stream>>>(in, invn, accum);
    finalize_kernel<<<1, 64, 0, stream>>>(accum, out);
  }
}

// Round 17
// 45.609 us; speedup vs baseline: 1.2233x; 1.2233x over previous
//
#include <hip/hip_runtime.h>
#include <stdint.h>

#define MARGIN 0.3f
#define NROWS 4096
#define DIM   2048
#define ROWB  1024                  // fp4: DIM/2 bytes per row
#define BT    128
#define BKB   128                   // bytes per row per K-step (256 elements)
#define NKS   (ROWB / BKB)          // 8 K-steps
#define NB    (NROWS / BT)          // 32
#define NBLK  (NB * (NB + 1) / 2)   // 528 (divisible by 8 -> clean XCD swizzle)

typedef float f32x4 __attribute__((ext_vector_type(4)));
typedef int   i32x4 __attribute__((ext_vector_type(4)));
typedef int   i32x8 __attribute__((ext_vector_type(8)));
typedef short s16x8 __attribute__((ext_vector_type(8)));

__device__ __forceinline__ ushort f32_to_bf16(float f) {
  uint32_t u = __float_as_uint(f);
  return (ushort)((u + 0x7FFFu + ((u >> 16) & 1u)) >> 16);
}

// e2m1 quantizer, RNE to grid {0,.5,1,1.5,2,3,4,6}, clamp at 6.
__device__ __forceinline__ unsigned f32_to_fp4(float y) {
  unsigned s = (__float_as_uint(y) >> 31) << 3;
  float a = fabsf(y);
  unsigned c;
  if      (a < 0.25f) c = 0;
  else if (a < 0.75f) c = 1;
  else if (a < 1.25f) c = 2;
  else if (a < 1.75f) c = 3;
  else if (a < 2.5f)  c = 4;
  else if (a < 3.5f)  c = 5;
  else if (a < 5.0f)  c = 6;
  else                c = 7;
  return s | c;
}

// async global->LDS, 16B per lane. LDS dest is wave-uniform base + lane*16
// (linear). Swizzle is carried on the GLOBAL source address.
__device__ __forceinline__ void async_load16(const void* g, void* l) {
  __builtin_amdgcn_global_load_lds(
      (const __attribute__((address_space(1))) uint32_t*)g,
      (__attribute__((address_space(3))) uint32_t*)l, 16, 0, 0);
}

// ---------------------------------------------------------------------------
// prep (R10 verbatim): row L2-norm -> normalized fp4(e2m1) row-major matrix at
// scale 2^6 (undone by the MFMA scale operand). Zeroes accum[0..1] and the
// completion counter (accum[2] as uint).
// ---------------------------------------------------------------------------
__global__ __launch_bounds__(256) void prep_kernel(const float* __restrict__ in,
                                                   unsigned char* __restrict__ pn,
                                                   float* __restrict__ accum) {
  const int row = blockIdx.x;
  const int tid = threadIdx.x;
  if (row == 0 && tid == 0) {
    accum[0] = 0.f; accum[1] = 0.f;
    ((unsigned*)accum)[2] = 0u;       // completion counter
  }

  const float4* rp = (const float4*)(in + (size_t)row * DIM);
  float4 v0 = rp[tid * 2];
  float4 v1 = rp[tid * 2 + 1];
  float ss = v0.x*v0.x + v0.y*v0.y + v0.z*v0.z + v0.w*v0.w
           + v1.x*v1.x + v1.y*v1.y + v1.z*v1.z + v1.w*v1.w;
  #pragma unroll
  for (int off = 32; off; off >>= 1) ss += __shfl_down(ss, off);

  __shared__ float wred[4];
  __shared__ float stot;
  const int lane = tid & 63, w = tid >> 6;
  if (lane == 0) wred[w] = ss;
  __syncthreads();
  if (tid == 0) stot = wred[0] + wred[1] + wred[2] + wred[3];
  __syncthreads();
  const float inv = 1.0f / fmaxf(sqrtf(stot), 1e-12f);

  const float sc = inv * 64.0f;            // pre-scale by 2^6
  float e[8] = {v0.x, v0.y, v0.z, v0.w, v1.x, v1.y, v1.z, v1.w};
  uint32_t u = 0;
  #pragma unroll
  for (int j = 0; j < 4; ++j) {
    unsigned lo = f32_to_fp4(e[2*j]   * sc);
    unsigned hi = f32_to_fp4(e[2*j+1] * sc);
    u |= (lo | (hi << 4)) << (8 * j);
  }
  *(uint32_t*)(pn + (size_t)row * ROWB + tid * 4) = u;
}

// ---------------------------------------------------------------------------
// tri_gemm (R10 verbatim + fused finalize): one block per upper-triangular
// 128x128 super-tile of sim = Pn Pn^T. fp4 e2m1 via
// mfma_scale_f32_16x16x128_f8f6f4 (cbsz=blgp=4), scale 0x79 = 2^-6 -> acc =
// sim directly. 256 threads = 4 waves (2x2), wave tile 64x64 (4x4 frags),
// BK=256 elems (128B/row) -> 8 K-steps. LDS: 2x16KB panels, 8-slot x 16B
// rows with R2-verified slot XOR (slot ^ (row&7)) -> conflict-free b128
// reads (0 measured). Staging: global_load_lds 16B/lane, linear LDS dest,
// swizzle on the GLOBAL source address. 2-barrier rolled loop.
// FUSED FINALIZE: last block (device-scope counter) reads accum coherently
// (atomicAdd(p,0)) and writes out[0]; resets counter for the next replay.
// ---------------------------------------------------------------------------
__global__ __launch_bounds__(256) void tri_gemm(const unsigned char* __restrict__ pn,
                                                float* __restrict__ accum,
                                                float* __restrict__ out) {
  // XCD-aware bijective swizzle (NBLK % 8 == 0)
  const int b = blockIdx.x;
  int t = (b & 7) * (NBLK / 8) + (b >> 3);
  int bi = 0;
  while (t >= NB - bi) { t -= NB - bi; ++bi; }
  const int bj = bi + t;

  __shared__ __align__(16) unsigned char Asm[BT * BKB];   // 16 KB
  __shared__ __align__(16) unsigned char Bsm[BT * BKB];   // 16 KB

  const int tid  = threadIdx.x;
  const int lane = tid & 63;
  const int w    = tid >> 6;          // 0..3
  const int wr   = w >> 1;            // 0..1
  const int wc   = w & 1;             // 0..1

  f32x4 acc[4][4] = {};
  const int rowA = bi * BT, rowB = bj * BT;

  // staging: 1 KB chunk = 8 rows x 128 B; lane l -> row +(l>>3), stored slot
  // (l&7); global true-k slot = (l&7) ^ (l>>3)   [row&7 == l>>3]
  const int srow  = (lane >> 3);
  const int gslot = (lane & 7) ^ srow;

  const unsigned char* gA = pn + (size_t)(rowA + srow) * ROWB + gslot * 16;
  const unsigned char* gB = pn + (size_t)(rowB + srow) * ROWB + gslot * 16;

  const int fr = lane & 15, g = lane >> 4;
  const i32x4 z4 = {0, 0, 0, 0};

  for (int ks = 0; ks < NKS; ++ks) {
    const int kb = ks * BKB;          // byte offset within row
    if (ks) __syncthreads();          // prior reads done before overwrite
    #pragma unroll
    for (int q = 0; q < 4; ++q) {
      const int r = w * 32 + q * 8;   // chunk base row (multiple of 8)
      async_load16(gA + (size_t)r * ROWB + kb, Asm + r * BKB);
      async_load16(gB + (size_t)r * ROWB + kb, Bsm + r * BKB);
    }
    __syncthreads();                  // vmcnt(0) drain: data visible

    // sub-K kk covers true k-bytes [kk*64, kk*64+64); lane's 16B for kgroup g
    // sits at stored slot (kk*4 + g) ^ (row&7). One ds_read_b128 each.
    #pragma unroll
    for (int kk = 0; kk < 2; ++kk) {
      i32x8 af[4], bf[4];
      #pragma unroll
      for (int m = 0; m < 4; ++m) {
        const int ra = wr * 64 + m * 16 + fr;
        i32x4 va = *(const i32x4*)(Asm + ra * BKB + (((kk * 4 + g) ^ (ra & 7)) * 16));
        af[m] = __builtin_shufflevector(va, z4, 0, 1, 2, 3, 4, 5, 6, 7);
        const int rb = wc * 64 + m * 16 + fr;
        i32x4 vb = *(const i32x4*)(Bsm + rb * BKB + (((kk * 4 + g) ^ (rb & 7)) * 16));
        bf[m] = __builtin_shufflevector(vb, z4, 0, 1, 2, 3, 4, 5, 6, 7);
      }
      #pragma unroll
      for (int m = 0; m < 4; ++m)
        #pragma unroll
        for (int n = 0; n < 4; ++n)
          acc[m][n] = __builtin_amdgcn_mfma_scale_f32_16x16x128_f8f6f4(
              af[m], bf[n], acc[m][n],
              4, 4,                      // cbsz=fp4(e2m1), blgp=fp4(e2m1)
              0, 0x79797979,             // scale_a: e8m0 = 2^-6 everywhere
              0, 0x79797979);            // scale_b: e8m0 = 2^-6 everywhere
    }
  }

  // ---- epilogue: mask + reduce (C/D layout is shape-determined) ----
  float lsum = 0.f, lcnt = 0.f;
  const int gib = rowA + wr * 64;
  const int gjb = rowB + wc * 64;
  #pragma unroll
  for (int m = 0; m < 4; ++m) {
    #pragma unroll
    for (int n = 0; n < 4; ++n) {
      #pragma unroll
      for (int r = 0; r < 4; ++r) {
        int gi = gib + m * 16 + (lane >> 4) * 4 + r;
        int gj = gjb + n * 16 + (lane & 15);
        float s = acc[m][n][r];
        if (gi < gj && s > MARGIN) { lsum += s - MARGIN; lcnt += 1.f; }
      }
    }
  }
  #pragma unroll
  for (int off = 32; off; off >>= 1) {
    lsum += __shfl_down(lsum, off);
    lcnt += __shfl_down(lcnt, off);
  }
  __shared__ float rs[4], rc[4];
  if (lane == 0) { rs[w] = lsum; rc[w] = lcnt; }
  __syncthreads();
  if (tid == 0) {
    atomicAdd(&accum[0], rs[0] + rs[1] + rs[2] + rs[3]);
    atomicAdd(&accum[1], rc[0] + rc[1] + rc[2] + rc[3]);
    // ---- fused finalize: last block computes the output ----
    __threadfence();                            // publish adds device-wide
    unsigned* ctr = (unsigned*)accum + 2;
    unsigned old = atomicAdd(ctr, 1u);
    if (old == (unsigned)(NBLK - 1)) {
      float s = atomicAdd(&accum[0], 0.f);      // coherent cross-XCD reads
      float c = atomicAdd(&accum[1], 0.f);
      out[0] = (c < 0.5f) ? 0.0f : s / c;
      atomicExch(ctr, 0u);                      // reset for next graph replay
    }
  }
}

// ---------------------------------------------------------------------------
// Fallback (tiny workspace): bf16 on-the-fly convert (verified R2 structure),
// separate finalize.
// ---------------------------------------------------------------------------
__global__ __launch_bounds__(256) void prep_inv(const float* __restrict__ in,
                                                float* __restrict__ invn,
                                                float* __restrict__ accum) {
  const int row = blockIdx.x;
  const int tid = threadIdx.x;
  if (row == 0 && tid == 0) { accum[0] = 0.f; accum[1] = 0.f; }
  const float4* rp = (const float4*)(in + (size_t)row * DIM);
  float4 v0 = rp[tid * 2];
  float4 v1 = rp[tid * 2 + 1];
  float ss = v0.x*v0.x + v0.y*v0.y + v0.z*v0.z + v0.w*v0.w
           + v1.x*v1.x + v1.y*v1.y + v1.z*v1.z + v1.w*v1.w;
  #pragma unroll
  for (int off = 32; off; off >>= 1) ss += __shfl_down(ss, off);
  __shared__ float wred[4];
  const int lane = tid & 63, w = tid >> 6;
  if (lane == 0) wred[w] = ss;
  __syncthreads();
  if (tid == 0)
    invn[row] = 1.0f / fmaxf(sqrtf(wred[0] + wred[1] + wred[2] + wred[3]), 1e-12f);
}

__global__ __launch_bounds__(256) void tri_gemm_fly(const float* __restrict__ inF,
                                                    const float* __restrict__ invn,
                                                    float* __restrict__ accum) {
  enum { FBK = 64 };
  int t = blockIdx.x, bi = 0;
  while (t >= NB - bi) { t -= NB - bi; ++bi; }
  const int bj = bi + t;

  __shared__ __align__(16) ushort Asm[BT * FBK];
  __shared__ __align__(16) ushort Bsm[BT * FBK];

  const int tid  = threadIdx.x;
  const int lane = tid & 63;
  const int w    = tid >> 6;
  const int wr   = w >> 1, wc = w & 1;

  f32x4 acc[4][4] = {};
  const int rowA = bi * BT, rowB = bj * BT;

  for (int k0 = 0; k0 < DIM; k0 += FBK) {
    if (k0) __syncthreads();
    #pragma unroll
    for (int p = 0; p < 8; ++p) {
      int c   = p * 256 + tid;
      int isB = c >> 10;
      int cc  = c & 1023;
      int r   = cc >> 3;
      int s   = cc & 7;
      const int grow = (isB ? rowB : rowA) + r;
      const float4* src = (const float4*)(inF + (size_t)grow * DIM + k0 + s * 8);
      float4 v0 = src[0], v1 = src[1];
      int4 pack;
      ushort* h = (ushort*)&pack;
      h[0] = f32_to_bf16(v0.x); h[1] = f32_to_bf16(v0.y);
      h[2] = f32_to_bf16(v0.z); h[3] = f32_to_bf16(v0.w);
      h[4] = f32_to_bf16(v1.x); h[5] = f32_to_bf16(v1.y);
      h[6] = f32_to_bf16(v1.z); h[7] = f32_to_bf16(v1.w);
      *(int4*)((isB ? Bsm : Asm) + r * FBK + (s ^ (r & 7)) * 8) = pack;
    }
    __syncthreads();

    s16x8 af[2][4], bfv[2][4];
    const int fr = lane & 15, hi = lane >> 4;
    #pragma unroll
    for (int kk = 0; kk < 2; ++kk)
      #pragma unroll
      for (int m = 0; m < 4; ++m) {
        const int ra = wr * 64 + m * 16 + fr;
        af[kk][m] = *(const s16x8*)(Asm + ra * FBK + ((kk * 4 + hi) ^ (ra & 7)) * 8);
        const int rb = wc * 64 + m * 16 + fr;
        bfv[kk][m] = *(const s16x8*)(Bsm + rb * FBK + ((kk * 4 + hi) ^ (rb & 7)) * 8);
      }
    #pragma unroll
    for (int kk = 0; kk < 2; ++kk)
      #pragma unroll
      for (int m = 0; m < 4; ++m)
        #pragma unroll
        for (int n = 0; n < 4; ++n)
          acc[m][n] = __builtin_amdgcn_mfma_f32_16x16x32_bf16(af[kk][m], bfv[kk][n],
                                                              acc[m][n], 0, 0, 0);
  }

  float lsum = 0.f, lcnt = 0.f;
  const int gib = rowA + wr * 64;
  const int gjb = rowB + wc * 64;
  #pragma unroll
  for (int m = 0; m < 4; ++m)
    #pragma unroll
    for (int n = 0; n < 4; ++n)
      #pragma unroll
      for (int r = 0; r < 4; ++r) {
        int gi = gib + m * 16 + (lane >> 4) * 4 + r;
        int gj = gjb + n * 16 + (lane & 15);
        float s = acc[m][n][r] * invn[gi] * invn[gj];
        if (gi < gj && s > MARGIN) { lsum += s - MARGIN; lcnt += 1.f; }
      }
  #pragma unroll
  for (int off = 32; off; off >>= 1) {
    lsum += __shfl_down(lsum, off);
    lcnt += __shfl_down(lcnt, off);
  }
  __shared__ float rs[4], rc[4];
  if (lane == 0) { rs[w] = lsum; rc[w] = lcnt; }
  __syncthreads();
  if (tid == 0) {
    atomicAdd(&accum[0], rs[0] + rs[1] + rs[2] + rs[3]);
    atomicAdd(&accum[1], rc[0] + rc[1] + rc[2] + rc[3]);
  }
}

__global__ void finalize_kernel(const float* __restrict__ accum, float* __restrict__ out) {
  if (threadIdx.x == 0) out[0] = (accum[1] < 0.5f) ? 0.0f : accum[0] / accum[1];
}

extern "C" void kernel_launch(void* const* d_in, const int* in_sizes, int n_in,
                              void* d_out, int out_size, void* d_ws, size_t ws_size,
                              hipStream_t stream) {
  const float* in = (const float*)d_in[0];
  float* out = (float*)d_out;
  const size_t pn_bytes = (size_t)NROWS * ROWB;   // fp4: 4.2 MB

  if (ws_size >= pn_bytes + 4 * sizeof(float)) {
    unsigned char* pn = (unsigned char*)d_ws;
    float* accum = (float*)((char*)d_ws + pn_bytes);   // [sum, cnt, ctr]
    prep_kernel<<<NROWS, 256, 0, stream>>>(in, pn, accum);
    tri_gemm<<<NBLK, 256, 0, stream>>>(pn, accum, out);
  } else {
    float* invn  = (float*)d_ws;
    float* accum = (float*)((char*)d_ws + NROWS * sizeof(float));
    prep_inv<<<NROWS, 256, 0, stream>>>(in, invn, accum);
    tri_gemm_fly<<<NBLK, 256, 0, stream>>>(in, invn, accum);
    finalize_kernel<<<1, 64, 0, stream>>>(accum, out);
  }
}